// Round 4
// baseline (794.817 us; speedup 1.0000x reference)
//
#include <hip/hip_runtime.h>
#include <hip/hip_bf16.h>
#include <cstddef>

#define NSTOCK 100
#define LOG2E 1.4426950408889634f

typedef _Float16 f16x8 __attribute__((ext_vector_type(8)));
typedef float f32x16 __attribute__((ext_vector_type(16)));

static __device__ __forceinline__ float rcpf(float x){ return __builtin_amdgcn_rcpf(x); }
static __device__ __forceinline__ float exp2f_(float x){ return __builtin_amdgcn_exp2f(x); }

// ---------------------------------------------------------------------------
// prep: build permuted+scaled weight matrix Wp[512][144] and biasp[512].
// perm slot p = w*64 + nt*32 + q  (w=wave, nt=tile, q=lane&31):
//   type = nt*2 + (q>>4)  (0=i,1=f,2=g,3=o),  j = w*16 + (q&15)
//   orig gate = type*120 + j   (pad if j>=120)
// k: 0..15 = x features (W_ih), 16..135 = h (W_hh), 136..143 pad.
// rows pre-scaled by log2e (sigmoid) / 2*log2e (tanh g-row).
// ---------------------------------------------------------------------------
__global__ void prep_kernel(const float* __restrict__ W_ih,
                            const float* __restrict__ W_hh,
                            const float* __restrict__ b_ih,
                            const float* __restrict__ b_hh,
                            float* __restrict__ Wp,
                            float* __restrict__ biasp) {
    int idx = blockIdx.x * 256 + threadIdx.x;
    if (idx < 512 * 144) {
        int k = idx % 144;
        int p = idx / 144;
        int w = p >> 6, r = p & 63, nt = r >> 5, q = r & 31;
        int type = nt * 2 + (q >> 4);
        int j = w * 16 + (q & 15);
        float v = 0.f;
        if (j < 120 && k < 136) {
            int g = type * 120 + j;
            v = (k < 16) ? W_ih[g * 16 + k] : W_hh[g * 120 + (k - 16)];
            v *= (type == 2) ? 2.f * LOG2E : LOG2E;
        }
        Wp[idx] = v;
    }
    if (idx < 512) {
        int p = idx;
        int w = p >> 6, r = p & 63, nt = r >> 5, q = r & 31;
        int type = nt * 2 + (q >> 4);
        int j = w * 16 + (q & 15);
        float v = 0.f;
        if (j < 120) {
            int g = type * 120 + j;
            v = (b_ih[g] + b_hh[g]) * ((type == 2) ? 2.f * LOG2E : LOG2E);
        }
        biasp[idx] = v;
    }
}

// ---------------------------------------------------------------------------
// lstm: 200 blocks x 512 thr, 32 batch rows/block, 128 steps in-block.
// Weights persistent in registers (fp16 split hi/lo), A-operand (x|h) staged
// in double-buffered LDS fragment layout, activations in-register via
// shfl_xor(16) pair exchange. fp32-equivalent via 3-term fp16-split MFMA.
// __launch_bounds__(512, 2): 2 waves/EU -> 256-VGPR cap. Weight frags alone
// need 144 VGPRs; the default cap (128) spilled them to scratch and the
// t-loop reloaded them every step (round-3: 735 us, MfmaUtil 21%).
// ---------------------------------------------------------------------------
__global__ __launch_bounds__(512, 2) void lstm_kernel(
        const float* __restrict__ x,
        const float* __restrict__ Wp,
        const float* __restrict__ biasp,
        const float* __restrict__ w_lin,
        const float* __restrict__ b_lin,
        float* __restrict__ s_out) {
    __shared__ __align__(16) _Float16 fragHi[2][9][64][8];
    __shared__ __align__(16) _Float16 fragLo[2][9][64][8];
    __shared__ float sred[15][32];

    const int tid   = threadIdx.x;
    const int lane  = tid & 63;
    const int w     = tid >> 6;        // wave 0..7
    const int l31   = lane & 31;
    const int lhalf = lane >> 5;
    const int n0    = blockIdx.x * 32;

    // ---- persistent weight fragments ----
    f16x8 bh[2][9], bl[2][9];
#pragma unroll
    for (int nt = 0; nt < 2; ++nt) {
        const int p = w * 64 + nt * 32 + l31;
#pragma unroll
        for (int kt = 0; kt < 9; ++kt) {
            const float* wp = Wp + p * 144 + kt * 16 + lhalf * 8;
            f16x8 hi, lo;
#pragma unroll
            for (int e = 0; e < 8; ++e) {
                float v = wp[e];
                _Float16 h_ = (_Float16)v;
                hi[e] = h_;
                lo[e] = (_Float16)(v - (float)h_);
            }
            bh[nt][kt] = hi; bl[nt][kt] = lo;
        }
    }
    const float bias0 = biasp[w * 64 + l31];
    const float bias1 = biasp[w * 64 + 32 + l31];

    // ---- zero h-region (kt 1..8) of both buffers ----
    {
        f16x8 z;
#pragma unroll
        for (int e = 0; e < 8; ++e) z[e] = (_Float16)0.f;
        for (int ii = tid; ii < 2 * 8 * 64; ii += 512) {
            int bf = ii >> 9, kt = 1 + ((ii >> 6) & 7), ln = ii & 63;
            *(f16x8*)&fragHi[bf][kt][ln][0] = z;
            *(f16x8*)&fragLo[bf][kt][ln][0] = z;
        }
    }

    // ---- x staging (wave 0): thread -> (batch bx, half halfx) ----
    const int bx = lane >> 1;
    const int halfx = lane & 1;
    const int nx = n0 + bx;
    const int bbx = nx / NSTOCK, ssx = nx % NSTOCK;
    const float* xbase = x + (size_t)bbx * 204800 + ssx * 16 + halfx * 8;
    if (w == 0) {   // stage x_0 into buf 0
        float4 v0 = *(const float4*)(xbase);
        float4 v1 = *(const float4*)(xbase + 4);
        float vv[8] = {v0.x, v0.y, v0.z, v0.w, v1.x, v1.y, v1.z, v1.w};
        f16x8 hi, lo;
#pragma unroll
        for (int e = 0; e < 8; ++e) {
            _Float16 h_ = (_Float16)vv[e];
            hi[e] = h_; lo[e] = (_Float16)(vv[e] - (float)h_);
        }
        *(f16x8*)&fragHi[0][0][bx + 32 * halfx][0] = hi;
        *(f16x8*)&fragLo[0][0][bx + 32 * halfx][0] = lo;
    }
    __syncthreads();

    // activation lane constants
    const int jj  = lane & 15;            // j within wave: j = w*16 + jj
    const int sel = (lane >> 4) & 1;      // 0: holds i(g), 1: holds f(o)
    const bool actv = (w * 16 + jj) < 120;
    const int ktw = 1 + w;                // frag kt this wave writes
    const int wlane = (jj >> 3);          // frag lane-half from jj
    const int welem = jj & 7;

    float creg[8];
#pragma unroll
    for (int e = 0; e < 8; ++e) creg[e] = 0.f;

    for (int t = 0; t < 128; ++t) {
        const int rb = t & 1;
        const int wb = rb ^ 1;
        // prefetch x_{t+1} (wave 0) — latency hidden under GEMM
        float4 xv0, xv1;
        if (w == 0) {
            int tt = (t < 127) ? t + 1 : 127;
            const float* xp = xbase + (size_t)tt * 1600;
            xv0 = *(const float4*)xp;
            xv1 = *(const float4*)(xp + 4);
        }
        // ---- GEMM: preacts = [x|h] @ Wp^T + bias (split-fp16, fp32 acc) ----
        f32x16 acc0, acc1;
#pragma unroll
        for (int r = 0; r < 16; ++r) { acc0[r] = bias0; acc1[r] = bias1; }
#pragma unroll
        for (int kt = 0; kt < 9; ++kt) {
            f16x8 ah = *(const f16x8*)&fragHi[rb][kt][lane][0];
            f16x8 al = *(const f16x8*)&fragLo[rb][kt][lane][0];
            acc0 = __builtin_amdgcn_mfma_f32_32x32x16_f16(ah, bh[0][kt], acc0, 0, 0, 0);
            acc1 = __builtin_amdgcn_mfma_f32_32x32x16_f16(ah, bh[1][kt], acc1, 0, 0, 0);
            acc0 = __builtin_amdgcn_mfma_f32_32x32x16_f16(ah, bl[0][kt], acc0, 0, 0, 0);
            acc1 = __builtin_amdgcn_mfma_f32_32x32x16_f16(ah, bl[1][kt], acc1, 0, 0, 0);
            acc0 = __builtin_amdgcn_mfma_f32_32x32x16_f16(al, bh[0][kt], acc0, 0, 0, 0);
            acc1 = __builtin_amdgcn_mfma_f32_32x32x16_f16(al, bh[1][kt], acc1, 0, 0, 0);
        }
        // ---- activation, in-register; lane pair (m, m+16) swaps i/f and g/o
        // lane sel=0 computes batch rows r_eff=rr, sel=1 rows r_eff=rr+8.
#pragma unroll
        for (int rr = 0; rr < 8; ++rr) {
            float send0 = sel ? acc0[rr] : acc0[rr + 8];
            float send1 = sel ? acc1[rr] : acc1[rr + 8];
            float recv0 = __shfl_xor(send0, 16);
            float recv1 = __shfl_xor(send1, 16);
            float own0 = sel ? acc0[rr + 8] : acc0[rr];
            float own1 = sel ? acc1[rr + 8] : acc1[rr];
            float iv = sel ? recv0 : own0;
            float fv = sel ? own0 : recv0;
            float gv = sel ? recv1 : own1;
            float ov = sel ? own1 : recv1;
            // preacts pre-scaled by log2e (2*log2e for g)
            float si = rcpf(1.f + exp2f_(-iv));
            float sf = rcpf(1.f + exp2f_(-fv));
            float tg = 1.f - 2.f * rcpf(1.f + exp2f_(gv));
            float so = rcpf(1.f + exp2f_(-ov));
            float c = sf * creg[rr] + si * tg;
            creg[rr] = c;
            float h = so * (1.f - 2.f * rcpf(1.f + exp2f_(c * 2.8853900817779268f)));
            if (actv) {
                _Float16 hh = (_Float16)h;
                _Float16 hl = (_Float16)(h - (float)hh);
                int b_row = (rr & 3) + 8 * (rr >> 2) + 16 * sel + 4 * lhalf;
                fragHi[wb][ktw][b_row + 32 * wlane][welem] = hh;
                fragLo[wb][ktw][b_row + 32 * wlane][welem] = hl;
            }
        }
        // ---- stage x_{t+1} into write buffer (wave 0) ----
        if (w == 0) {
            float vv[8] = {xv0.x, xv0.y, xv0.z, xv0.w, xv1.x, xv1.y, xv1.z, xv1.w};
            f16x8 hi, lo;
#pragma unroll
            for (int e = 0; e < 8; ++e) {
                _Float16 h_ = (_Float16)vv[e];
                hi[e] = h_; lo[e] = (_Float16)(vv[e] - (float)h_);
            }
            *(f16x8*)&fragHi[wb][0][bx + 32 * halfx][0] = hi;
            *(f16x8*)&fragLo[wb][0][bx + 32 * halfx][0] = lo;
        }
        __syncthreads();
    }

    // ---- s = h_last . w_lin + b_lin  (final h is in buffer 0) ----
    if (tid < 480) {
        const int b = tid & 31;
        const int jg = tid >> 5;                 // 0..14, j = jg*8+e
        const int lane_ = b + 32 * (jg & 1);
        const int ktE = 1 + (jg >> 1);
        f16x8 hi = *(const f16x8*)&fragHi[0][ktE][lane_][0];
        f16x8 lo = *(const f16x8*)&fragLo[0][ktE][lane_][0];
        float sp = 0.f;
#pragma unroll
        for (int e = 0; e < 8; ++e)
            sp += ((float)hi[e] + (float)lo[e]) * w_lin[jg * 8 + e];
        sred[jg][b] = sp;
    }
    __syncthreads();
    if (tid < 32) {
        float s = b_lin[0];
#pragma unroll
        for (int jg2 = 0; jg2 < 15; ++jg2) s += sred[jg2][tid];
        s_out[n0 + tid] = s;
    }
}

// ---------------------------------------------------------------------------
// phat: per batch b, NeuralSort relaxed perm matrix -> fooT[m][b] (transposed)
// ---------------------------------------------------------------------------
__global__ __launch_bounds__(128) void phat_kernel(const float* __restrict__ s,
                                                   float* __restrict__ fooT) {
    __shared__ float a[NSTOCK], c[NSTOCK];
    const int b = blockIdx.x, tid = threadIdx.x;
    const float* sb = s + b * NSTOCK;
    if (tid < NSTOCK) {
        float sj = sb[tid];
        float rs = 0.f;
        for (int i2 = 0; i2 < NSTOCK; ++i2) rs += fabsf(sj - sb[i2]);
        a[tid] = sj * 0.2f;
        c[tid] = rs * 0.2f;
    }
    __syncthreads();
    if (tid < NSTOCK) {
        const int i = tid;
        const float sci = (float)(99 - 2 * i);
        float m = -1e30f;
        for (int j = 0; j < NSTOCK; ++j) m = fmaxf(m, sci * a[j] - c[j]);
        float sum = 0.f;
        for (int j = 0; j < NSTOCK; ++j) sum += __expf(sci * a[j] - c[j] - m);
        const float inv = 1.f / sum;
        for (int j = 0; j < NSTOCK; ++j)
            fooT[(size_t)(i * NSTOCK + j) * 64 + b] = __expf(sci * a[j] - c[j] - m) * inv;
    }
}

// ---------------------------------------------------------------------------
// mlp1: z2T[u][b] = relu(sum_m fooT[m][b]*W2[u][m] + b2[u])
// 4 u per block, 8 waves each over a 1250-m chunk, LDS cross-wave reduce.
// ---------------------------------------------------------------------------
__global__ __launch_bounds__(512) void mlp1_kernel(const float* __restrict__ fooT,
                                                   const float* __restrict__ W2,
                                                   const float* __restrict__ b2,
                                                   float* __restrict__ z2T) {
    __shared__ float part[8][4][64];
    const int tid = threadIdx.x;
    const int wv = tid >> 6, lane = tid & 63;
    const int u0 = blockIdx.x * 4;
    const int m0 = wv * 1250;
    float a0 = 0.f, a1 = 0.f, a2 = 0.f, a3 = 0.f;
    for (int mi = 0; mi < 1250; ++mi) {
        int m = m0 + mi;
        float v = fooT[(size_t)m * 64 + lane];
        a0 += v * W2[(size_t)(u0 + 0) * 10000 + m];
        a1 += v * W2[(size_t)(u0 + 1) * 10000 + m];
        a2 += v * W2[(size_t)(u0 + 2) * 10000 + m];
        a3 += v * W2[(size_t)(u0 + 3) * 10000 + m];
    }
    part[wv][0][lane] = a0; part[wv][1][lane] = a1;
    part[wv][2][lane] = a2; part[wv][3][lane] = a3;
    __syncthreads();
    if (tid < 256) {
        int q = tid >> 6, b = tid & 63;
        float s = b2[u0 + q];
#pragma unroll
        for (int w2 = 0; w2 < 8; ++w2) s += part[w2][q][b];
        z2T[(u0 + q) * 64 + b] = fmaxf(s, 0.f);
    }
}

// ---------------------------------------------------------------------------
// mlp2: z3[b][v] = sum_u z2[b][u]*W3[v][u] + b3[v]; out = softmax_v
// ---------------------------------------------------------------------------
__global__ __launch_bounds__(128) void mlp2_kernel(const float* __restrict__ z2T,
                                                   const float* __restrict__ W3,
                                                   const float* __restrict__ b3,
                                                   float* __restrict__ out) {
    __shared__ float zs[256];
    __shared__ float logits[NSTOCK];
    const int b = blockIdx.x, tid = threadIdx.x;
    for (int u = tid; u < 256; u += 128) zs[u] = z2T[u * 64 + b];
    __syncthreads();
    if (tid < NSTOCK) {
        float acc = b3[tid];
        const float* wr = W3 + tid * 256;
        for (int u = 0; u < 256; ++u) acc += zs[u] * wr[u];
        logits[tid] = acc;
    }
    __syncthreads();
    if (tid < NSTOCK) {
        float m = -1e30f;
        for (int j = 0; j < NSTOCK; ++j) m = fmaxf(m, logits[j]);
        float sum = 0.f;
        for (int j = 0; j < NSTOCK; ++j) sum += __expf(logits[j] - m);
        out[b * NSTOCK + tid] = __expf(logits[tid] - m) / sum;
    }
}

// ---------------------------------------------------------------------------
extern "C" void kernel_launch(void* const* d_in, const int* in_sizes, int n_in,
                              void* d_out, int out_size, void* d_ws, size_t ws_size,
                              hipStream_t stream) {
    const float* x     = (const float*)d_in[0];
    const float* W_ih  = (const float*)d_in[1];
    const float* W_hh  = (const float*)d_in[2];
    const float* b_ih  = (const float*)d_in[3];
    const float* b_hh  = (const float*)d_in[4];
    const float* w_lin = (const float*)d_in[5];
    const float* b_lin = (const float*)d_in[6];
    const float* W2    = (const float*)d_in[7];
    const float* b2    = (const float*)d_in[8];
    const float* W3    = (const float*)d_in[9];
    const float* b3    = (const float*)d_in[10];

    float* ws    = (float*)d_ws;
    float* Wp    = ws;                 // 512*144 = 73728
    float* biasp = ws + 73728;         // 512
    float* sbuf  = ws + 74240;         // 6400
    float* fooT  = ws + 80640;         // 10000*64 = 640000
    float* z2T   = ws + 720640;        // 256*64 = 16384
    float* out   = (float*)d_out;

    prep_kernel<<<288, 256, 0, stream>>>(W_ih, W_hh, b_ih, b_hh, Wp, biasp);
    lstm_kernel<<<200, 512, 0, stream>>>(x, Wp, biasp, w_lin, b_lin, sbuf);
    phat_kernel<<<64, 128, 0, stream>>>(sbuf, fooT);
    mlp1_kernel<<<64, 512, 0, stream>>>(fooT, W2, b2, z2T);
    mlp2_kernel<<<64, 128, 0, stream>>>(z2T, W3, b3, out);
}

// Round 5
// 609.918 us; speedup vs baseline: 1.3032x; 1.3032x over previous
//
#include <hip/hip_runtime.h>
#include <hip/hip_bf16.h>
#include <cstddef>

#define NSTOCK 100
#define LOG2E 1.4426950408889634f

typedef _Float16 f16x8 __attribute__((ext_vector_type(8)));
typedef float f32x16 __attribute__((ext_vector_type(16)));

static __device__ __forceinline__ float rcpf(float x){ return __builtin_amdgcn_rcpf(x); }
static __device__ __forceinline__ float exp2f_(float x){ return __builtin_amdgcn_exp2f(x); }

// ---------------------------------------------------------------------------
// prep: build permuted+scaled weight matrix Wp[512][144] and biasp[512].
// perm slot p = w*64 + nt*32 + q  (w=wave, nt=tile, q=lane&31):
//   type = nt*2 + (q>>4)  (0=i,1=f,2=g,3=o),  j = w*16 + (q&15)
//   orig gate = type*120 + j   (pad if j>=120)
// k: 0..15 = x features (W_ih), 16..135 = h (W_hh), 136..143 pad.
// rows pre-scaled by log2e (sigmoid) / 2*log2e (tanh g-row).
// ---------------------------------------------------------------------------
__global__ void prep_kernel(const float* __restrict__ W_ih,
                            const float* __restrict__ W_hh,
                            const float* __restrict__ b_ih,
                            const float* __restrict__ b_hh,
                            float* __restrict__ Wp,
                            float* __restrict__ biasp) {
    int idx = blockIdx.x * 256 + threadIdx.x;
    if (idx < 512 * 144) {
        int k = idx % 144;
        int p = idx / 144;
        int w = p >> 6, r = p & 63, nt = r >> 5, q = r & 31;
        int type = nt * 2 + (q >> 4);
        int j = w * 16 + (q & 15);
        float v = 0.f;
        if (j < 120 && k < 136) {
            int g = type * 120 + j;
            v = (k < 16) ? W_ih[g * 16 + k] : W_hh[g * 120 + (k - 16)];
            v *= (type == 2) ? 2.f * LOG2E : LOG2E;
        }
        Wp[idx] = v;
    }
    if (idx < 512) {
        int p = idx;
        int w = p >> 6, r = p & 63, nt = r >> 5, q = r & 31;
        int type = nt * 2 + (q >> 4);
        int j = w * 16 + (q & 15);
        float v = 0.f;
        if (j < 120) {
            int g = type * 120 + j;
            v = (b_ih[g] + b_hh[g]) * ((type == 2) ? 2.f * LOG2E : LOG2E);
        }
        biasp[idx] = v;
    }
}

// ---------------------------------------------------------------------------
// lstm: 200 blocks x 512 thr, 32 batch rows/block, 128 steps in-block.
// Weights persistent in registers (fp16 split hi/lo), A-operand (x|h) staged
// in double-buffered LDS fragment layout, activations in-register via
// shfl_xor(16) pair exchange. fp32-equivalent via 3-term fp16-split MFMA.
//
// amdgpu_waves_per_eu(2,2): pin allocator to 2 waves/EU -> 256-reg unified
// budget (launch_bounds(512,2) in round 4 was a no-op: VGPR stayed 128).
// Accumulators split into K-half chains (kt 0-4 / 5-8): 4 independent MFMA
// dep-chains, round-robin issue -> per-chain gap ~32cyc >= dependent latency
// (round-4 counters: 27.5 cyc/MFMA pipe occupancy = acc-hazard stall).
// ---------------------------------------------------------------------------
__global__ __launch_bounds__(512)
__attribute__((amdgpu_waves_per_eu(2, 2)))
void lstm_kernel(
        const float* __restrict__ x,
        const float* __restrict__ Wp,
        const float* __restrict__ biasp,
        const float* __restrict__ w_lin,
        const float* __restrict__ b_lin,
        float* __restrict__ s_out) {
    __shared__ __align__(16) _Float16 fragHi[2][9][64][8];
    __shared__ __align__(16) _Float16 fragLo[2][9][64][8];
    __shared__ float sred[15][32];

    const int tid   = threadIdx.x;
    const int lane  = tid & 63;
    const int w     = tid >> 6;        // wave 0..7
    const int l31   = lane & 31;
    const int lhalf = lane >> 5;
    const int n0    = blockIdx.x * 32;

    // ---- persistent weight fragments ----
    f16x8 bh[2][9], bl[2][9];
#pragma unroll
    for (int nt = 0; nt < 2; ++nt) {
        const int p = w * 64 + nt * 32 + l31;
#pragma unroll
        for (int kt = 0; kt < 9; ++kt) {
            const float* wp = Wp + p * 144 + kt * 16 + lhalf * 8;
            f16x8 hi, lo;
#pragma unroll
            for (int e = 0; e < 8; ++e) {
                float v = wp[e];
                _Float16 h_ = (_Float16)v;
                hi[e] = h_;
                lo[e] = (_Float16)(v - (float)h_);
            }
            bh[nt][kt] = hi; bl[nt][kt] = lo;
        }
    }
    const float bias0 = biasp[w * 64 + l31];
    const float bias1 = biasp[w * 64 + 32 + l31];

    // ---- zero h-region (kt 1..8) of both buffers ----
    {
        f16x8 z;
#pragma unroll
        for (int e = 0; e < 8; ++e) z[e] = (_Float16)0.f;
        for (int ii = tid; ii < 2 * 8 * 64; ii += 512) {
            int bf = ii >> 9, kt = 1 + ((ii >> 6) & 7), ln = ii & 63;
            *(f16x8*)&fragHi[bf][kt][ln][0] = z;
            *(f16x8*)&fragLo[bf][kt][ln][0] = z;
        }
    }

    // ---- x staging (wave 0): thread -> (batch bx, half halfx) ----
    const int bx = lane >> 1;
    const int halfx = lane & 1;
    const int nx = n0 + bx;
    const int bbx = nx / NSTOCK, ssx = nx % NSTOCK;
    const float* xbase = x + (size_t)bbx * 204800 + ssx * 16 + halfx * 8;
    if (w == 0) {   // stage x_0 into buf 0
        float4 v0 = *(const float4*)(xbase);
        float4 v1 = *(const float4*)(xbase + 4);
        float vv[8] = {v0.x, v0.y, v0.z, v0.w, v1.x, v1.y, v1.z, v1.w};
        f16x8 hi, lo;
#pragma unroll
        for (int e = 0; e < 8; ++e) {
            _Float16 h_ = (_Float16)vv[e];
            hi[e] = h_; lo[e] = (_Float16)(vv[e] - (float)h_);
        }
        *(f16x8*)&fragHi[0][0][bx + 32 * halfx][0] = hi;
        *(f16x8*)&fragLo[0][0][bx + 32 * halfx][0] = lo;
    }
    __syncthreads();

    // activation lane constants
    const int jj  = lane & 15;            // j within wave: j = w*16 + jj
    const int sel = (lane >> 4) & 1;      // 0: holds i(g), 1: holds f(o)
    const bool actv = (w * 16 + jj) < 120;
    const int ktw = 1 + w;                // frag kt this wave writes
    const int wlane = (jj >> 3);          // frag lane-half from jj
    const int welem = jj & 7;

    float creg[8];
#pragma unroll
    for (int e = 0; e < 8; ++e) creg[e] = 0.f;

    for (int t = 0; t < 128; ++t) {
        const int rb = t & 1;
        const int wb = rb ^ 1;
        // prefetch x_{t+1} (wave 0) — latency hidden under GEMM
        float4 xv0, xv1;
        if (w == 0) {
            int tt = (t < 127) ? t + 1 : 127;
            const float* xp = xbase + (size_t)tt * 1600;
            xv0 = *(const float4*)xp;
            xv1 = *(const float4*)(xp + 4);
        }
        // ---- GEMM: preacts = [x|h] @ Wp^T + bias (split-fp16, fp32 acc) ----
        // 4 independent acc chains (tile 0/1 x K-half a/b), issue round-robin.
        f32x16 acc0a, acc1a, acc0b, acc1b;
#pragma unroll
        for (int r = 0; r < 16; ++r) {
            acc0a[r] = bias0; acc1a[r] = bias1;
            acc0b[r] = 0.f;  acc1b[r] = 0.f;
        }
#pragma unroll
        for (int ktp = 0; ktp < 5; ++ktp) {
            const int ka = ktp;        // 0..4  -> chains a
            const int kb = ktp + 5;    // 5..8  -> chains b
            f16x8 ahA = *(const f16x8*)&fragHi[rb][ka][lane][0];
            f16x8 alA = *(const f16x8*)&fragLo[rb][ka][lane][0];
            f16x8 ahB, alB;
            if (ktp < 4) {
                ahB = *(const f16x8*)&fragHi[rb][kb][lane][0];
                alB = *(const f16x8*)&fragLo[rb][kb][lane][0];
            }
            acc0a = __builtin_amdgcn_mfma_f32_32x32x16_f16(ahA, bh[0][ka], acc0a, 0, 0, 0);
            acc1a = __builtin_amdgcn_mfma_f32_32x32x16_f16(ahA, bh[1][ka], acc1a, 0, 0, 0);
            if (ktp < 4) {
                acc0b = __builtin_amdgcn_mfma_f32_32x32x16_f16(ahB, bh[0][kb], acc0b, 0, 0, 0);
                acc1b = __builtin_amdgcn_mfma_f32_32x32x16_f16(ahB, bh[1][kb], acc1b, 0, 0, 0);
            }
            acc0a = __builtin_amdgcn_mfma_f32_32x32x16_f16(ahA, bl[0][ka], acc0a, 0, 0, 0);
            acc1a = __builtin_amdgcn_mfma_f32_32x32x16_f16(ahA, bl[1][ka], acc1a, 0, 0, 0);
            if (ktp < 4) {
                acc0b = __builtin_amdgcn_mfma_f32_32x32x16_f16(ahB, bl[0][kb], acc0b, 0, 0, 0);
                acc1b = __builtin_amdgcn_mfma_f32_32x32x16_f16(ahB, bl[1][kb], acc1b, 0, 0, 0);
            }
            acc0a = __builtin_amdgcn_mfma_f32_32x32x16_f16(alA, bh[0][ka], acc0a, 0, 0, 0);
            acc1a = __builtin_amdgcn_mfma_f32_32x32x16_f16(alA, bh[1][ka], acc1a, 0, 0, 0);
            if (ktp < 4) {
                acc0b = __builtin_amdgcn_mfma_f32_32x32x16_f16(alB, bh[0][kb], acc0b, 0, 0, 0);
                acc1b = __builtin_amdgcn_mfma_f32_32x32x16_f16(alB, bh[1][kb], acc1b, 0, 0, 0);
            }
        }
        f32x16 acc0, acc1;
#pragma unroll
        for (int r = 0; r < 16; ++r) {
            acc0[r] = acc0a[r] + acc0b[r];
            acc1[r] = acc1a[r] + acc1b[r];
        }
        // ---- activation, in-register; lane pair (m, m+16) swaps i/f and g/o
        // lane sel=0 computes batch rows r_eff=rr, sel=1 rows r_eff=rr+8.
#pragma unroll
        for (int rr = 0; rr < 8; ++rr) {
            float send0 = sel ? acc0[rr] : acc0[rr + 8];
            float send1 = sel ? acc1[rr] : acc1[rr + 8];
            float recv0 = __shfl_xor(send0, 16);
            float recv1 = __shfl_xor(send1, 16);
            float own0 = sel ? acc0[rr + 8] : acc0[rr];
            float own1 = sel ? acc1[rr + 8] : acc1[rr];
            float iv = sel ? recv0 : own0;
            float fv = sel ? own0 : recv0;
            float gv = sel ? recv1 : own1;
            float ov = sel ? own1 : recv1;
            // preacts pre-scaled by log2e (2*log2e for g)
            float si = rcpf(1.f + exp2f_(-iv));
            float sf = rcpf(1.f + exp2f_(-fv));
            float tg = 1.f - 2.f * rcpf(1.f + exp2f_(gv));
            float so = rcpf(1.f + exp2f_(-ov));
            float c = sf * creg[rr] + si * tg;
            creg[rr] = c;
            float h = so * (1.f - 2.f * rcpf(1.f + exp2f_(c * 2.8853900817779268f)));
            if (actv) {
                _Float16 hh = (_Float16)h;
                _Float16 hl = (_Float16)(h - (float)hh);
                int b_row = (rr & 3) + 8 * (rr >> 2) + 16 * sel + 4 * lhalf;
                fragHi[wb][ktw][b_row + 32 * wlane][welem] = hh;
                fragLo[wb][ktw][b_row + 32 * wlane][welem] = hl;
            }
        }
        // ---- stage x_{t+1} into write buffer (wave 0) ----
        if (w == 0) {
            float vv[8] = {xv0.x, xv0.y, xv0.z, xv0.w, xv1.x, xv1.y, xv1.z, xv1.w};
            f16x8 hi, lo;
#pragma unroll
            for (int e = 0; e < 8; ++e) {
                _Float16 h_ = (_Float16)vv[e];
                hi[e] = h_; lo[e] = (_Float16)(vv[e] - (float)h_);
            }
            *(f16x8*)&fragHi[wb][0][bx + 32 * halfx][0] = hi;
            *(f16x8*)&fragLo[wb][0][bx + 32 * halfx][0] = lo;
        }
        __syncthreads();
    }

    // ---- s = h_last . w_lin + b_lin  (final h is in buffer 0) ----
    if (tid < 480) {
        const int b = tid & 31;
        const int jg = tid >> 5;                 // 0..14, j = jg*8+e
        const int lane_ = b + 32 * (jg & 1);
        const int ktE = 1 + (jg >> 1);
        f16x8 hi = *(const f16x8*)&fragHi[0][ktE][lane_][0];
        f16x8 lo = *(const f16x8*)&fragLo[0][ktE][lane_][0];
        float sp = 0.f;
#pragma unroll
        for (int e = 0; e < 8; ++e)
            sp += ((float)hi[e] + (float)lo[e]) * w_lin[jg * 8 + e];
        sred[jg][b] = sp;
    }
    __syncthreads();
    if (tid < 32) {
        float s = b_lin[0];
#pragma unroll
        for (int jg2 = 0; jg2 < 15; ++jg2) s += sred[jg2][tid];
        s_out[n0 + tid] = s;
    }
}

// ---------------------------------------------------------------------------
// phat: per batch b, NeuralSort relaxed perm matrix -> fooT[m][b] (transposed)
// ---------------------------------------------------------------------------
__global__ __launch_bounds__(128) void phat_kernel(const float* __restrict__ s,
                                                   float* __restrict__ fooT) {
    __shared__ float a[NSTOCK], c[NSTOCK];
    const int b = blockIdx.x, tid = threadIdx.x;
    const float* sb = s + b * NSTOCK;
    if (tid < NSTOCK) {
        float sj = sb[tid];
        float rs = 0.f;
        for (int i2 = 0; i2 < NSTOCK; ++i2) rs += fabsf(sj - sb[i2]);
        a[tid] = sj * 0.2f;
        c[tid] = rs * 0.2f;
    }
    __syncthreads();
    if (tid < NSTOCK) {
        const int i = tid;
        const float sci = (float)(99 - 2 * i);
        float m = -1e30f;
        for (int j = 0; j < NSTOCK; ++j) m = fmaxf(m, sci * a[j] - c[j]);
        float sum = 0.f;
        for (int j = 0; j < NSTOCK; ++j) sum += __expf(sci * a[j] - c[j] - m);
        const float inv = 1.f / sum;
        for (int j = 0; j < NSTOCK; ++j)
            fooT[(size_t)(i * NSTOCK + j) * 64 + b] = __expf(sci * a[j] - c[j] - m) * inv;
    }
}

// ---------------------------------------------------------------------------
// mlp1: z2T[u][b] = relu(sum_m fooT[m][b]*W2[u][m] + b2[u])
// 4 u per block, 8 waves each over a 1250-m chunk, LDS cross-wave reduce.
// ---------------------------------------------------------------------------
__global__ __launch_bounds__(512) void mlp1_kernel(const float* __restrict__ fooT,
                                                   const float* __restrict__ W2,
                                                   const float* __restrict__ b2,
                                                   float* __restrict__ z2T) {
    __shared__ float part[8][4][64];
    const int tid = threadIdx.x;
    const int wv = tid >> 6, lane = tid & 63;
    const int u0 = blockIdx.x * 4;
    const int m0 = wv * 1250;
    float a0 = 0.f, a1 = 0.f, a2 = 0.f, a3 = 0.f;
    for (int mi = 0; mi < 1250; ++mi) {
        int m = m0 + mi;
        float v = fooT[(size_t)m * 64 + lane];
        a0 += v * W2[(size_t)(u0 + 0) * 10000 + m];
        a1 += v * W2[(size_t)(u0 + 1) * 10000 + m];
        a2 += v * W2[(size_t)(u0 + 2) * 10000 + m];
        a3 += v * W2[(size_t)(u0 + 3) * 10000 + m];
    }
    part[wv][0][lane] = a0; part[wv][1][lane] = a1;
    part[wv][2][lane] = a2; part[wv][3][lane] = a3;
    __syncthreads();
    if (tid < 256) {
        int q = tid >> 6, b = tid & 63;
        float s = b2[u0 + q];
#pragma unroll
        for (int w2 = 0; w2 < 8; ++w2) s += part[w2][q][b];
        z2T[(u0 + q) * 64 + b] = fmaxf(s, 0.f);
    }
}

// ---------------------------------------------------------------------------
// mlp2: z3[b][v] = sum_u z2[b][u]*W3[v][u] + b3[v]; out = softmax_v
// ---------------------------------------------------------------------------
__global__ __launch_bounds__(128) void mlp2_kernel(const float* __restrict__ z2T,
                                                   const float* __restrict__ W3,
                                                   const float* __restrict__ b3,
                                                   float* __restrict__ out) {
    __shared__ float zs[256];
    __shared__ float logits[NSTOCK];
    const int b = blockIdx.x, tid = threadIdx.x;
    for (int u = tid; u < 256; u += 128) zs[u] = z2T[u * 64 + b];
    __syncthreads();
    if (tid < NSTOCK) {
        float acc = b3[tid];
        const float* wr = W3 + tid * 256;
        for (int u = 0; u < 256; ++u) acc += zs[u] * wr[u];
        logits[tid] = acc;
    }
    __syncthreads();
    if (tid < NSTOCK) {
        float m = -1e30f;
        for (int j = 0; j < NSTOCK; ++j) m = fmaxf(m, logits[j]);
        float sum = 0.f;
        for (int j = 0; j < NSTOCK; ++j) sum += __expf(logits[j] - m);
        out[b * NSTOCK + tid] = __expf(logits[tid] - m) / sum;
    }
}

// ---------------------------------------------------------------------------
extern "C" void kernel_launch(void* const* d_in, const int* in_sizes, int n_in,
                              void* d_out, int out_size, void* d_ws, size_t ws_size,
                              hipStream_t stream) {
    const float* x     = (const float*)d_in[0];
    const float* W_ih  = (const float*)d_in[1];
    const float* W_hh  = (const float*)d_in[2];
    const float* b_ih  = (const float*)d_in[3];
    const float* b_hh  = (const float*)d_in[4];
    const float* w_lin = (const float*)d_in[5];
    const float* b_lin = (const float*)d_in[6];
    const float* W2    = (const float*)d_in[7];
    const float* b2    = (const float*)d_in[8];
    const float* W3    = (const float*)d_in[9];
    const float* b3    = (const float*)d_in[10];

    float* ws    = (float*)d_ws;
    float* Wp    = ws;                 // 512*144 = 73728
    float* biasp = ws + 73728;         // 512
    float* sbuf  = ws + 74240;         // 6400
    float* fooT  = ws + 80640;         // 10000*64 = 640000
    float* z2T   = ws + 720640;        // 256*64 = 16384
    float* out   = (float*)d_out;

    prep_kernel<<<288, 256, 0, stream>>>(W_ih, W_hh, b_ih, b_hh, Wp, biasp);
    lstm_kernel<<<200, 512, 0, stream>>>(x, Wp, biasp, w_lin, b_lin, sbuf);
    phat_kernel<<<64, 128, 0, stream>>>(sbuf, fooT);
    mlp1_kernel<<<64, 512, 0, stream>>>(fooT, W2, b2, z2T);
    mlp2_kernel<<<64, 128, 0, stream>>>(z2T, W3, b3, out);
}

// Round 6
// 515.972 us; speedup vs baseline: 1.5404x; 1.1821x over previous
//
#include <hip/hip_runtime.h>
#include <hip/hip_bf16.h>
#include <cstddef>

#define NSTOCK 100
#define LOG2E 1.4426950408889634f

typedef _Float16 f16x8 __attribute__((ext_vector_type(8)));
typedef float f32x16 __attribute__((ext_vector_type(16)));

static __device__ __forceinline__ float rcpf(float x){ return __builtin_amdgcn_rcpf(x); }
static __device__ __forceinline__ float exp2f_(float x){ return __builtin_amdgcn_exp2f(x); }

// ---------------------------------------------------------------------------
// prep: permuted+scaled weights Wp[480][144], biasp[480].
// slot p = w*32 + type*8 + jj  (w=wave 0..14, type 0..3 = i,f,g,o, jj 0..7)
// j = w*8 + jj (0..119), orig gate row g = type*120 + j.
// k: 0..15 x feats (W_ih), 16..135 h (W_hh), 136..143 zero pad.
// Scale baked: sigmoid rows (i,f,o) * -log2e  -> act = rcp(1+exp2(pre))
//              tanh row  (g)      * +2log2e  -> act = 1-2*rcp(1+exp2(pre))
// ---------------------------------------------------------------------------
__global__ void prep_kernel(const float* __restrict__ W_ih,
                            const float* __restrict__ W_hh,
                            const float* __restrict__ b_ih,
                            const float* __restrict__ b_hh,
                            float* __restrict__ Wp,
                            float* __restrict__ biasp) {
    int idx = blockIdx.x * 256 + threadIdx.x;
    if (idx < 480 * 144) {
        int k = idx % 144;
        int p = idx / 144;
        int w = p >> 5, q = p & 31, type = q >> 3, jj = q & 7;
        int j = w * 8 + jj;            // always < 120
        int g = type * 120 + j;
        float v = 0.f;
        if (k < 136) v = (k < 16) ? W_ih[g * 16 + k] : W_hh[g * 120 + (k - 16)];
        v *= (type == 2) ? 2.f * LOG2E : -LOG2E;
        Wp[idx] = v;
    }
    if (idx < 480) {
        int p = idx;
        int w = p >> 5, q = p & 31, type = q >> 3, jj = q & 7;
        int j = w * 8 + jj;
        int g = type * 120 + j;
        biasp[idx] = (b_ih[g] + b_hh[g]) * ((type == 2) ? 2.f * LOG2E : -LOG2E);
    }
}

// ---------------------------------------------------------------------------
// lstm: 200 blocks x 1024 thr (16 waves, 4/SIMD), 32 batch rows/block.
// Waves 0..14: each owns 32 gate slots (1 N-tile); B-frags 72 VGPR -> fits
// 128-reg budget at 4 waves/SIMD (4x latency hiding vs round-5's 2).
// Wave 15: dedicated x stager. A-frags (x|h, fp16 hi/lo) double-buffered in
// LDS. Activation applied per-column pre-exchange (scales sign-baked), then
// 2-round shfl_xor(8/16) butterfly gathers i,f,g,o per (b,j) in-register.
// 3-term fp16-split MFMA (ah*bh + ah*bl + al*bh) == fp32 accuracy.
// ---------------------------------------------------------------------------
__global__ __launch_bounds__(1024) void lstm_kernel(
        const float* __restrict__ x,
        const float* __restrict__ Wp,
        const float* __restrict__ biasp,
        const float* __restrict__ w_lin,
        const float* __restrict__ b_lin,
        float* __restrict__ s_out) {
    __shared__ __align__(16) _Float16 AHi[2][9][64][8];
    __shared__ __align__(16) _Float16 ALo[2][9][64][8];
    __shared__ float sred[15][32];

    const int tid   = threadIdx.x;
    const int lane  = tid & 63;
    const int w     = tid >> 6;        // wave 0..15
    const int l31   = lane & 31;
    const int lhalf = lane >> 5;
    const int n0    = blockIdx.x * 32;

    // ---- persistent weight fragments (waves 0..14) ----
    f16x8 bh[9], bl[9];
    float biasv = 0.f;
    if (w < 15) {
        const int p = w * 32 + l31;
#pragma unroll
        for (int kt = 0; kt < 9; ++kt) {
            const float* wp = Wp + p * 144 + kt * 16 + lhalf * 8;
            f16x8 hi, lo;
#pragma unroll
            for (int e = 0; e < 8; ++e) {
                float v = wp[e];
                _Float16 h_ = (_Float16)v;
                hi[e] = h_;
                lo[e] = (_Float16)(v - (float)h_);
            }
            bh[kt] = hi; bl[kt] = lo;
        }
        biasv = biasp[p];
    }

    // ---- zero h-region (kt 1..8) of both buffers: 1024 rows, 1:1 ----
    {
        f16x8 z;
#pragma unroll
        for (int e = 0; e < 8; ++e) z[e] = (_Float16)0.f;
        int bf = tid >> 9, kt = 1 + ((tid >> 6) & 7), ln = tid & 63;
        *(f16x8*)&AHi[bf][kt][ln][0] = z;
        *(f16x8*)&ALo[bf][kt][ln][0] = z;
    }

    // ---- x staging geometry (wave 15): lane -> (row bx, half hx) ----
    const int bx = lane >> 1;
    const int hx = lane & 1;
    const int nx  = n0 + bx;
    const int bbx = nx / NSTOCK, ssx = nx % NSTOCK;
    const float* xbase = x + (size_t)bbx * 204800 + ssx * 16 + hx * 8;
    if (w == 15) {   // stage x_0 into buf 0
        float4 a0 = *(const float4*)xbase;
        float4 a1 = *(const float4*)(xbase + 4);
        float vv[8] = {a0.x, a0.y, a0.z, a0.w, a1.x, a1.y, a1.z, a1.w};
        f16x8 hi, lo;
#pragma unroll
        for (int e = 0; e < 8; ++e) {
            _Float16 h_ = (_Float16)vv[e];
            hi[e] = h_; lo[e] = (_Float16)(vv[e] - (float)h_);
        }
        *(f16x8*)&AHi[0][0][bx + 32 * hx][0] = hi;
        *(f16x8*)&ALo[0][0][bx + 32 * hx][0] = lo;
    }
    __syncthreads();

    // ---- activation lane constants ----
    const int t0s = (l31 >> 3) & 1;
    const int t1s = (l31 >> 4) & 1;
    const int typ = l31 >> 3;                   // own gate type
    const float aL  = (typ == 2) ? 1.f : 0.f;   // act = aL + bL*rcp(1+exp2(pre))
    const float bL  = (typ == 2) ? -2.f : 1.f;
    const int jj   = l31 & 7;
    const int myj  = w * 8 + jj;                // j this thread's elems belong to
    const int kidx = 16 + myj;                  // k index of h_j
    const int ktw  = kidx >> 4;
    const int wl2  = (kidx >> 3) & 1;
    const int wel  = kidx & 7;
    const int bbase = 8 * (2 * t0s + t1s) + 4 * lhalf;  // first owned batch row

    float creg[4] = {0.f, 0.f, 0.f, 0.f};

    for (int t = 0; t < 128; ++t) {
        const int rb = t & 1;
        const int wb = rb ^ 1;
        if (w == 15) {
            // ---- stage x_{t+1} into write buffer ----
            int tt = (t < 127) ? t + 1 : 127;
            const float* xp = xbase + (size_t)tt * 1600;
            float4 a0 = *(const float4*)xp;
            float4 a1 = *(const float4*)(xp + 4);
            float vv[8] = {a0.x, a0.y, a0.z, a0.w, a1.x, a1.y, a1.z, a1.w};
            f16x8 hi, lo;
#pragma unroll
            for (int e = 0; e < 8; ++e) {
                _Float16 h_ = (_Float16)vv[e];
                hi[e] = h_; lo[e] = (_Float16)(vv[e] - (float)h_);
            }
            *(f16x8*)&AHi[wb][0][bx + 32 * hx][0] = hi;
            *(f16x8*)&ALo[wb][0][bx + 32 * hx][0] = lo;
        } else {
            // ---- GEMM: 27 MFMA, single acc chain (4 waves/SIMD feed pipe) --
            f32x16 acc;
#pragma unroll
            for (int r = 0; r < 16; ++r) acc[r] = biasv;
#pragma unroll
            for (int kt = 0; kt < 9; ++kt) {
                f16x8 ah = *(const f16x8*)&AHi[rb][kt][lane][0];
                f16x8 al = *(const f16x8*)&ALo[rb][kt][lane][0];
                acc = __builtin_amdgcn_mfma_f32_32x32x16_f16(ah, bh[kt], acc, 0, 0, 0);
                acc = __builtin_amdgcn_mfma_f32_32x32x16_f16(ah, bl[kt], acc, 0, 0, 0);
                acc = __builtin_amdgcn_mfma_f32_32x32x16_f16(al, bh[kt], acc, 0, 0, 0);
            }
            // ---- per-column activation (scales/sign baked in weights) ----
            float av[16];
#pragma unroll
            for (int r = 0; r < 16; ++r)
                av[r] = aL + bL * rcpf(1.f + exp2f_(acc[r]));
            // ---- butterfly exchange: rows split by t0 (8/8), t1 (4/4) ----
            float v1[8], u[8];
#pragma unroll
            for (int k2 = 0; k2 < 8; ++k2) {
                float snd = t0s ? av[k2] : av[8 + k2];
                v1[k2] = __shfl_xor(snd, 8);           // partner-type, kept rows
                u[k2]  = t0s ? av[8 + k2] : av[k2];    // own-type, kept rows
            }
#pragma unroll
            for (int k2 = 0; k2 < 4; ++k2) {
                float w0 = t1s ? u[4 + k2] : u[k2];     // type own^0
                float s2 = t1s ? u[k2] : u[4 + k2];
                float w2 = __shfl_xor(s2, 16);          // type own^2
                float w1 = t1s ? v1[4 + k2] : v1[k2];   // type own^1
                float s3 = t1s ? v1[k2] : v1[4 + k2];
                float w3 = __shfl_xor(s3, 16);          // type own^3
                // i*g is the symmetric pair product; f/o resolved by 4 selects
                float ig = t0s ? (w1 * w3) : (w0 * w2);
                float p  = t0s ? w0 : w1;
                float q  = t0s ? w2 : w3;
                float fv = t1s ? q : p;
                float ov = t1s ? p : q;
                float c  = fv * creg[k2] + ig;
                creg[k2] = c;
                float th = 1.f - 2.f * rcpf(1.f + exp2f_(c * 2.8853900817779268f));
                float h  = ov * th;
                _Float16 hh = (_Float16)h;
                _Float16 hl = (_Float16)(h - (float)hh);
                AHi[wb][ktw][bbase + k2 + 32 * wl2][wel] = hh;
                ALo[wb][ktw][bbase + k2 + 32 * wl2][wel] = hl;
            }
        }
        __syncthreads();
    }

    // ---- s = h_last . w_lin + b_lin  (final h is in buffer 0) ----
    if (tid < 480) {
        const int b  = tid & 31;
        const int jg = tid >> 5;                 // 0..14, j = jg*8+e
        const int lane_ = b + 32 * (jg & 1);
        const int ktE = 1 + (jg >> 1);
        f16x8 hi = *(const f16x8*)&AHi[0][ktE][lane_][0];
        f16x8 lo = *(const f16x8*)&ALo[0][ktE][lane_][0];
        float sp = 0.f;
#pragma unroll
        for (int e = 0; e < 8; ++e)
            sp += ((float)hi[e] + (float)lo[e]) * w_lin[jg * 8 + e];
        sred[jg][b] = sp;
    }
    __syncthreads();
    if (tid < 32) {
        float s = b_lin[0];
#pragma unroll
        for (int jg2 = 0; jg2 < 15; ++jg2) s += sred[jg2][tid];
        s_out[n0 + tid] = s;
    }
}

// ---------------------------------------------------------------------------
// phat: per batch b, NeuralSort relaxed perm matrix -> fooT[m][b] (transposed)
// ---------------------------------------------------------------------------
__global__ __launch_bounds__(128) void phat_kernel(const float* __restrict__ s,
                                                   float* __restrict__ fooT) {
    __shared__ float a[NSTOCK], c[NSTOCK];
    const int b = blockIdx.x, tid = threadIdx.x;
    const float* sb = s + b * NSTOCK;
    if (tid < NSTOCK) {
        float sj = sb[tid];
        float rs = 0.f;
        for (int i2 = 0; i2 < NSTOCK; ++i2) rs += fabsf(sj - sb[i2]);
        a[tid] = sj * 0.2f;
        c[tid] = rs * 0.2f;
    }
    __syncthreads();
    if (tid < NSTOCK) {
        const int i = tid;
        const float sci = (float)(99 - 2 * i);
        float m = -1e30f;
        for (int j = 0; j < NSTOCK; ++j) m = fmaxf(m, sci * a[j] - c[j]);
        float sum = 0.f;
        for (int j = 0; j < NSTOCK; ++j) sum += __expf(sci * a[j] - c[j] - m);
        const float inv = 1.f / sum;
        for (int j = 0; j < NSTOCK; ++j)
            fooT[(size_t)(i * NSTOCK + j) * 64 + b] = __expf(sci * a[j] - c[j] - m) * inv;
    }
}

// ---------------------------------------------------------------------------
// mlp1: z2T[u][b] = relu(sum_m fooT[m][b]*W2[u][m] + b2[u])
// ---------------------------------------------------------------------------
__global__ __launch_bounds__(512) void mlp1_kernel(const float* __restrict__ fooT,
                                                   const float* __restrict__ W2,
                                                   const float* __restrict__ b2,
                                                   float* __restrict__ z2T) {
    __shared__ float part[8][4][64];
    const int tid = threadIdx.x;
    const int wv = tid >> 6, lane = tid & 63;
    const int u0 = blockIdx.x * 4;
    const int m0 = wv * 1250;
    float a0 = 0.f, a1 = 0.f, a2 = 0.f, a3 = 0.f;
    for (int mi = 0; mi < 1250; ++mi) {
        int m = m0 + mi;
        float v = fooT[(size_t)m * 64 + lane];
        a0 += v * W2[(size_t)(u0 + 0) * 10000 + m];
        a1 += v * W2[(size_t)(u0 + 1) * 10000 + m];
        a2 += v * W2[(size_t)(u0 + 2) * 10000 + m];
        a3 += v * W2[(size_t)(u0 + 3) * 10000 + m];
    }
    part[wv][0][lane] = a0; part[wv][1][lane] = a1;
    part[wv][2][lane] = a2; part[wv][3][lane] = a3;
    __syncthreads();
    if (tid < 256) {
        int q = tid >> 6, b = tid & 63;
        float s = b2[u0 + q];
#pragma unroll
        for (int w2 = 0; w2 < 8; ++w2) s += part[w2][q][b];
        z2T[(u0 + q) * 64 + b] = fmaxf(s, 0.f);
    }
}

// ---------------------------------------------------------------------------
// mlp2: z3[b][v] = sum_u z2[b][u]*W3[v][u] + b3[v]; out = softmax_v
// ---------------------------------------------------------------------------
__global__ __launch_bounds__(128) void mlp2_kernel(const float* __restrict__ z2T,
                                                   const float* __restrict__ W3,
                                                   const float* __restrict__ b3,
                                                   float* __restrict__ out) {
    __shared__ float zs[256];
    __shared__ float logits[NSTOCK];
    const int b = blockIdx.x, tid = threadIdx.x;
    for (int u = tid; u < 256; u += 128) zs[u] = z2T[u * 64 + b];
    __syncthreads();
    if (tid < NSTOCK) {
        float acc = b3[tid];
        const float* wr = W3 + tid * 256;
        for (int u = 0; u < 256; ++u) acc += zs[u] * wr[u];
        logits[tid] = acc;
    }
    __syncthreads();
    if (tid < NSTOCK) {
        float m = -1e30f;
        for (int j = 0; j < NSTOCK; ++j) m = fmaxf(m, logits[j]);
        float sum = 0.f;
        for (int j = 0; j < NSTOCK; ++j) sum += __expf(logits[j] - m);
        out[b * NSTOCK + tid] = __expf(logits[tid] - m) / sum;
    }
}

// ---------------------------------------------------------------------------
extern "C" void kernel_launch(void* const* d_in, const int* in_sizes, int n_in,
                              void* d_out, int out_size, void* d_ws, size_t ws_size,
                              hipStream_t stream) {
    const float* x     = (const float*)d_in[0];
    const float* W_ih  = (const float*)d_in[1];
    const float* W_hh  = (const float*)d_in[2];
    const float* b_ih  = (const float*)d_in[3];
    const float* b_hh  = (const float*)d_in[4];
    const float* w_lin = (const float*)d_in[5];
    const float* b_lin = (const float*)d_in[6];
    const float* W2    = (const float*)d_in[7];
    const float* b2    = (const float*)d_in[8];
    const float* W3    = (const float*)d_in[9];
    const float* b3    = (const float*)d_in[10];

    float* ws    = (float*)d_ws;
    float* Wp    = ws;                 // 480*144 = 69120
    float* biasp = ws + 69120;         // 480
    float* sbuf  = ws + 69600;         // 6400
    float* fooT  = ws + 76000;         // 10000*64 = 640000
    float* z2T   = ws + 716000;        // 256*64 = 16384
    float* out   = (float*)d_out;

    prep_kernel<<<271, 256, 0, stream>>>(W_ih, W_hh, b_ih, b_hh, Wp, biasp);
    lstm_kernel<<<200, 1024, 0, stream>>>(x, Wp, biasp, w_lin, b_lin, sbuf);
    phat_kernel<<<64, 128, 0, stream>>>(sbuf, fooT);
    mlp1_kernel<<<64, 512, 0, stream>>>(fooT, W2, b2, z2T);
    mlp2_kernel<<<64, 128, 0, stream>>>(z2T, W3, b3, out);
}

// Round 7
// 435.560 us; speedup vs baseline: 1.8248x; 1.1846x over previous
//
#include <hip/hip_runtime.h>
#include <hip/hip_bf16.h>
#include <cstddef>

#define NSTOCK 100
#define LOG2E 1.4426950408889634f

typedef _Float16 f16x8 __attribute__((ext_vector_type(8)));
typedef float f32x16 __attribute__((ext_vector_type(16)));

static __device__ __forceinline__ float rcpf(float x){ return __builtin_amdgcn_rcpf(x); }
static __device__ __forceinline__ float exp2f_(float x){ return __builtin_amdgcn_exp2f(x); }

// ---------------------------------------------------------------------------
// prep: permuted+scaled weights Wp[480][144].
// slot p = w*32 + row, row = 4*jj + type  (w=wave 0..14, jj 0..7, type i,f,g,o)
// j = w*8 + jj (0..119), orig gate row g = type*120 + j.
// k: 0..15 x feats (W_ih), 16..135 h (W_hh), 136 = bias column (B==1.0),
// 137..143 zero pad.
// Scale baked: sigmoid rows (i,f,o) * -log2e  -> act = rcp(1+exp2(pre))
//              tanh row  (g)      * +2log2e  -> act = 1-2*rcp(1+exp2(pre))
// ---------------------------------------------------------------------------
__global__ void prep_kernel(const float* __restrict__ W_ih,
                            const float* __restrict__ W_hh,
                            const float* __restrict__ b_ih,
                            const float* __restrict__ b_hh,
                            float* __restrict__ Wp) {
    int idx = blockIdx.x * 256 + threadIdx.x;
    if (idx < 480 * 144) {
        int k = idx % 144;
        int p = idx / 144;
        int w = p >> 5, row = p & 31, jj = row >> 2, type = row & 3;
        int j = w * 8 + jj;            // < 120
        int g = type * 120 + j;
        float scale = (type == 2) ? 2.f * LOG2E : -LOG2E;
        float v = 0.f;
        if (k < 136)       v = ((k < 16) ? W_ih[g * 16 + k] : W_hh[g * 120 + (k - 16)]) * scale;
        else if (k == 136) v = (b_ih[g] + b_hh[g]) * scale;   // bias col vs B==1
        Wp[idx] = v;
    }
}

// ---------------------------------------------------------------------------
// lstm: 200 blocks x 1024 thr (16 waves, 4/SIMD), 32 batch rows/block.
// OPERAND-SWAPPED GEMM: preact^T = Wp @ [x|h|1]^T. A = weights (rows = gate
// slots, persistent fp16 hi/lo regs), B = activations (LDS frag, layout
// Act[kt][l][e] = act[batch=l&31][k=kt*16+8*(l>>5)+e] -- unchanged from the
// verified round-6 layout). acc rows = gate slots: row = 4*jj + type, so each
// lane owns i,f,g,o for 4 j's of batch (lane&31) -> activation fully
// lane-local, ZERO cross-lane shuffles (round-6 spent ~16 ds_bpermute +
// ~40 select VALU per thread on the gate exchange).
// 3-term fp16-split MFMA (Wh*Ah + Wh*Al + Wl*Ah) == fp32 accuracy.
// ---------------------------------------------------------------------------
__global__ __launch_bounds__(1024) void lstm_kernel(
        const float* __restrict__ x,
        const float* __restrict__ Wp,
        const float* __restrict__ w_lin,
        const float* __restrict__ b_lin,
        float* __restrict__ s_out) {
    __shared__ __align__(16) _Float16 AHi[2][9][64][8];
    __shared__ __align__(16) _Float16 ALo[2][9][64][8];
    __shared__ float sred[15][32];

    const int tid   = threadIdx.x;
    const int lane  = tid & 63;
    const int w     = tid >> 6;        // wave 0..15
    const int l31   = lane & 31;
    const int lhalf = lane >> 5;
    const int n0    = blockIdx.x * 32;

    // ---- persistent weight fragments (waves 0..14): A-operand ----
    // lane l holds Wp[slot = w*32 + (l&31)][k = kt*16 + 8*(l>>5) + e]
    f16x8 bh[9], bl[9];
    if (w < 15) {
        const int p = w * 32 + l31;
#pragma unroll
        for (int kt = 0; kt < 9; ++kt) {
            const float* wp = Wp + p * 144 + kt * 16 + lhalf * 8;
            f16x8 hi, lo;
#pragma unroll
            for (int e = 0; e < 8; ++e) {
                float v = wp[e];
                _Float16 h_ = (_Float16)v;
                hi[e] = h_;
                lo[e] = (_Float16)(v - (float)h_);
            }
            bh[kt] = hi; bl[kt] = lo;
        }
    }

    // ---- zero h-region (kt 1..8) of both buffers: 1024 threads, 1:1 ----
    {
        f16x8 z;
#pragma unroll
        for (int e = 0; e < 8; ++e) z[e] = (_Float16)0.f;
        int bf = tid >> 9, kt = 1 + ((tid >> 6) & 7), ln = tid & 63;
        *(f16x8*)&AHi[bf][kt][ln][0] = z;
        *(f16x8*)&ALo[bf][kt][ln][0] = z;
    }
    __syncthreads();

    // ---- x staging geometry (wave 15): lane -> (row bx, half hx) ----
    const int bx = lane >> 1;
    const int hx = lane & 1;
    const int nx  = n0 + bx;
    const int bbx = nx / NSTOCK, ssx = nx % NSTOCK;
    const float* xbase = x + (size_t)bbx * 204800 + ssx * 16 + hx * 8;
    if (w == 15) {   // stage x_0 into buf 0
        float4 a0 = *(const float4*)xbase;
        float4 a1 = *(const float4*)(xbase + 4);
        float vv[8] = {a0.x, a0.y, a0.z, a0.w, a1.x, a1.y, a1.z, a1.w};
        f16x8 hi, lo;
#pragma unroll
        for (int e = 0; e < 8; ++e) {
            _Float16 h_ = (_Float16)vv[e];
            hi[e] = h_; lo[e] = (_Float16)(vv[e] - (float)h_);
        }
        *(f16x8*)&AHi[0][0][bx + 32 * hx][0] = hi;
        *(f16x8*)&ALo[0][0][bx + 32 * hx][0] = lo;
    }
    // ---- bias column: B[k=136][b] = 1.0, both buffers (never overwritten;
    //      k=136 -> kt=8, k15=8 -> ln = 32+b, e=0; ALo stays 0) ----
    if (tid < 64) {
        int buf = tid >> 5, b = tid & 31;
        AHi[buf][8][32 + b][0] = (_Float16)1.f;
    }
    __syncthreads();

    // ---- h-write lane constants: thread owns j = w*8 + 2p + lhalf, p=0..3,
    //      batch = l31. k=16+j -> AHi[wb][k>>4][l31 + 32*((k&15)>>3)][k&7]
    const int jbase = (w << 3) + lhalf;

    float creg[4] = {0.f, 0.f, 0.f, 0.f};

    for (int t = 0; t < 128; ++t) {
        const int rb = t & 1;
        const int wb = rb ^ 1;
        if (w == 15) {
            // ---- stage x_{t+1} into write buffer ----
            int tt = (t < 127) ? t + 1 : 127;
            const float* xp = xbase + (size_t)tt * 1600;
            float4 a0 = *(const float4*)xp;
            float4 a1 = *(const float4*)(xp + 4);
            float vv[8] = {a0.x, a0.y, a0.z, a0.w, a1.x, a1.y, a1.z, a1.w};
            f16x8 hi, lo;
#pragma unroll
            for (int e = 0; e < 8; ++e) {
                _Float16 h_ = (_Float16)vv[e];
                hi[e] = h_; lo[e] = (_Float16)(vv[e] - (float)h_);
            }
            *(f16x8*)&AHi[wb][0][bx + 32 * hx][0] = hi;
            *(f16x8*)&ALo[wb][0][bx + 32 * hx][0] = lo;
        } else {
            // ---- GEMM: 27 MFMA, acc[4p+type] = preact(type, j=jbase+2p) ----
            f32x16 acc;
#pragma unroll
            for (int r = 0; r < 16; ++r) acc[r] = 0.f;
#pragma unroll
            for (int kt = 0; kt < 9; ++kt) {
                f16x8 ah = *(const f16x8*)&AHi[rb][kt][lane][0];
                f16x8 al = *(const f16x8*)&ALo[rb][kt][lane][0];
                acc = __builtin_amdgcn_mfma_f32_32x32x16_f16(bh[kt], ah, acc, 0, 0, 0);
                acc = __builtin_amdgcn_mfma_f32_32x32x16_f16(bh[kt], al, acc, 0, 0, 0);
                acc = __builtin_amdgcn_mfma_f32_32x32x16_f16(bl[kt], ah, acc, 0, 0, 0);
            }
            // ---- lane-local activation (scales/sign baked in weights) ----
#pragma unroll
            for (int p = 0; p < 4; ++p) {
                float iv = rcpf(1.f + exp2f_(acc[4 * p + 0]));
                float fv = rcpf(1.f + exp2f_(acc[4 * p + 1]));
                float gv = 1.f - 2.f * rcpf(1.f + exp2f_(acc[4 * p + 2]));
                float ov = rcpf(1.f + exp2f_(acc[4 * p + 3]));
                float c = fv * creg[p] + iv * gv;
                creg[p] = c;
                float h = ov * (1.f - 2.f * rcpf(1.f + exp2f_(c * 2.8853900817779268f)));
                _Float16 hh = (_Float16)h;
                _Float16 hl = (_Float16)(h - (float)hh);
                int k   = 16 + jbase + 2 * p;
                int kt2 = k >> 4, k15 = k & 15;
                int ln  = l31 + 32 * (k15 >> 3), e = k15 & 7;
                AHi[wb][kt2][ln][e] = hh;
                ALo[wb][kt2][ln][e] = hl;
            }
        }
        __syncthreads();
    }

    // ---- s = h_last . w_lin + b_lin  (final h is in buffer 0) ----
    if (tid < 480) {
        const int b  = tid & 31;
        const int jg = tid >> 5;                 // 0..14, j = jg*8+e
        const int lane_ = b + 32 * (jg & 1);
        const int ktE = 1 + (jg >> 1);
        f16x8 hi = *(const f16x8*)&AHi[0][ktE][lane_][0];
        f16x8 lo = *(const f16x8*)&ALo[0][ktE][lane_][0];
        float sp = 0.f;
#pragma unroll
        for (int e = 0; e < 8; ++e)
            sp += ((float)hi[e] + (float)lo[e]) * w_lin[jg * 8 + e];
        sred[jg][b] = sp;
    }
    __syncthreads();
    if (tid < 32) {
        float s = b_lin[0];
#pragma unroll
        for (int jg2 = 0; jg2 < 15; ++jg2) s += sred[jg2][tid];
        s_out[n0 + tid] = s;
    }
}

// ---------------------------------------------------------------------------
// phat: per batch b, NeuralSort relaxed perm matrix -> fooT[m][b] (transposed)
// ---------------------------------------------------------------------------
__global__ __launch_bounds__(128) void phat_kernel(const float* __restrict__ s,
                                                   float* __restrict__ fooT) {
    __shared__ float a[NSTOCK], c[NSTOCK];
    const int b = blockIdx.x, tid = threadIdx.x;
    const float* sb = s + b * NSTOCK;
    if (tid < NSTOCK) {
        float sj = sb[tid];
        float rs = 0.f;
        for (int i2 = 0; i2 < NSTOCK; ++i2) rs += fabsf(sj - sb[i2]);
        a[tid] = sj * 0.2f;
        c[tid] = rs * 0.2f;
    }
    __syncthreads();
    if (tid < NSTOCK) {
        const int i = tid;
        const float sci = (float)(99 - 2 * i);
        float m = -1e30f;
        for (int j = 0; j < NSTOCK; ++j) m = fmaxf(m, sci * a[j] - c[j]);
        float sum = 0.f;
        for (int j = 0; j < NSTOCK; ++j) sum += __expf(sci * a[j] - c[j] - m);
        const float inv = 1.f / sum;
        for (int j = 0; j < NSTOCK; ++j)
            fooT[(size_t)(i * NSTOCK + j) * 64 + b] = __expf(sci * a[j] - c[j] - m) * inv;
    }
}

// ---------------------------------------------------------------------------
// mlp1: z2T[u][b] = relu(sum_m fooT[m][b]*W2[u][m] + b2[u])
// ---------------------------------------------------------------------------
__global__ __launch_bounds__(512) void mlp1_kernel(const float* __restrict__ fooT,
                                                   const float* __restrict__ W2,
                                                   const float* __restrict__ b2,
                                                   float* __restrict__ z2T) {
    __shared__ float part[8][4][64];
    const int tid = threadIdx.x;
    const int wv = tid >> 6, lane = tid & 63;
    const int u0 = blockIdx.x * 4;
    const int m0 = wv * 1250;
    float a0 = 0.f, a1 = 0.f, a2 = 0.f, a3 = 0.f;
    for (int mi = 0; mi < 1250; ++mi) {
        int m = m0 + mi;
        float v = fooT[(size_t)m * 64 + lane];
        a0 += v * W2[(size_t)(u0 + 0) * 10000 + m];
        a1 += v * W2[(size_t)(u0 + 1) * 10000 + m];
        a2 += v * W2[(size_t)(u0 + 2) * 10000 + m];
        a3 += v * W2[(size_t)(u0 + 3) * 10000 + m];
    }
    part[wv][0][lane] = a0; part[wv][1][lane] = a1;
    part[wv][2][lane] = a2; part[wv][3][lane] = a3;
    __syncthreads();
    if (tid < 256) {
        int q = tid >> 6, b = tid & 63;
        float s = b2[u0 + q];
#pragma unroll
        for (int w2 = 0; w2 < 8; ++w2) s += part[w2][q][b];
        z2T[(u0 + q) * 64 + b] = fmaxf(s, 0.f);
    }
}

// ---------------------------------------------------------------------------
// mlp2: z3[b][v] = sum_u z2[b][u]*W3[v][u] + b3[v]; out = softmax_v
// ---------------------------------------------------------------------------
__global__ __launch_bounds__(128) void mlp2_kernel(const float* __restrict__ z2T,
                                                   const float* __restrict__ W3,
                                                   const float* __restrict__ b3,
                                                   float* __restrict__ out) {
    __shared__ float zs[256];
    __shared__ float logits[NSTOCK];
    const int b = blockIdx.x, tid = threadIdx.x;
    for (int u = tid; u < 256; u += 128) zs[u] = z2T[u * 64 + b];
    __syncthreads();
    if (tid < NSTOCK) {
        float acc = b3[tid];
        const float* wr = W3 + tid * 256;
        for (int u = 0; u < 256; ++u) acc += zs[u] * wr[u];
        logits[tid] = acc;
    }
    __syncthreads();
    if (tid < NSTOCK) {
        float m = -1e30f;
        for (int j = 0; j < NSTOCK; ++j) m = fmaxf(m, logits[j]);
        float sum = 0.f;
        for (int j = 0; j < NSTOCK; ++j) sum += __expf(logits[j] - m);
        out[b * NSTOCK + tid] = __expf(logits[tid] - m) / sum;
    }
}

// ---------------------------------------------------------------------------
extern "C" void kernel_launch(void* const* d_in, const int* in_sizes, int n_in,
                              void* d_out, int out_size, void* d_ws, size_t ws_size,
                              hipStream_t stream) {
    const float* x     = (const float*)d_in[0];
    const float* W_ih  = (const float*)d_in[1];
    const float* W_hh  = (const float*)d_in[2];
    const float* b_ih  = (const float*)d_in[3];
    const float* b_hh  = (const float*)d_in[4];
    const float* w_lin = (const float*)d_in[5];
    const float* b_lin = (const float*)d_in[6];
    const float* W2    = (const float*)d_in[7];
    const float* b2    = (const float*)d_in[8];
    const float* W3    = (const float*)d_in[9];
    const float* b3    = (const float*)d_in[10];

    float* ws    = (float*)d_ws;
    float* Wp    = ws;                 // 480*144 = 69120
    float* sbuf  = ws + 69600;         // 6400
    float* fooT  = ws + 76000;         // 10000*64 = 640000
    float* z2T   = ws + 716000;        // 256*64 = 16384
    float* out   = (float*)d_out;

    prep_kernel<<<271, 256, 0, stream>>>(W_ih, W_hh, b_ih, b_hh, Wp);
    lstm_kernel<<<200, 1024, 0, stream>>>(x, Wp, w_lin, b_lin, sbuf);
    phat_kernel<<<64, 128, 0, stream>>>(sbuf, fooT);
    mlp1_kernel<<<64, 512, 0, stream>>>(fooT, W2, b2, z2T);
    mlp2_kernel<<<64, 128, 0, stream>>>(z2T, W3, b3, out);
}

// Round 8
// 434.446 us; speedup vs baseline: 1.8295x; 1.0026x over previous
//
#include <hip/hip_runtime.h>
#include <hip/hip_bf16.h>
#include <cstddef>

#define NSTOCK 100
#define LOG2E 1.4426950408889634f

typedef _Float16 f16x8 __attribute__((ext_vector_type(8)));
typedef _Float16 f16x4 __attribute__((ext_vector_type(4)));
typedef float f32x16 __attribute__((ext_vector_type(16)));

static __device__ __forceinline__ float rcpf(float x){ return __builtin_amdgcn_rcpf(x); }
static __device__ __forceinline__ float exp2f_(float x){ return __builtin_amdgcn_exp2f(x); }

// ---------------------------------------------------------------------------
// prep: permuted+scaled weights Wp[480][144].
// slot p = w*32 + row (w=wave 0..14, row 0..31):
//   type = row&3, jjf = row>>2, j = w*8 + (jjf&1)*4 + (jjf>>1)
// (j-remap vs round 7: thread (lhalf,p) then owns j = w*8+4*lhalf+p, whose
//  four h-values are CONTIGUOUS f16 in the frag row -> one b64 write.)
// k: 0..15 x feats (W_ih), 16..135 h (W_hh), 136 = bias column (B==1.0),
// 137..143 zero pad.
// Scale baked: sigmoid rows (i,f,o) * -log2e  -> act = rcp(1+exp2(pre))
//              tanh row  (g)      * +2log2e  -> act = 1-2*rcp(1+exp2(pre))
// ---------------------------------------------------------------------------
__global__ void prep_kernel(const float* __restrict__ W_ih,
                            const float* __restrict__ W_hh,
                            const float* __restrict__ b_ih,
                            const float* __restrict__ b_hh,
                            float* __restrict__ Wp) {
    int idx = blockIdx.x * 256 + threadIdx.x;
    if (idx < 480 * 144) {
        int k = idx % 144;
        int p = idx / 144;
        int w = p >> 5, row = p & 31, jjf = row >> 2, type = row & 3;
        int j = w * 8 + (jjf & 1) * 4 + (jjf >> 1);   // < 120
        int g = type * 120 + j;
        float scale = (type == 2) ? 2.f * LOG2E : -LOG2E;
        float v = 0.f;
        if (k < 136)       v = ((k < 16) ? W_ih[g * 16 + k] : W_hh[g * 120 + (k - 16)]) * scale;
        else if (k == 136) v = (b_ih[g] + b_hh[g]) * scale;   // bias col vs B==1
        Wp[idx] = v;
    }
}

// ---------------------------------------------------------------------------
// lstm: 200 blocks x 1024 thr (16 waves, 4/SIMD), 32 batch rows/block.
// Operand-swapped GEMM: preact^T = Wp @ [x|h|1]^T (A = weights in regs,
// B = activations in LDS frag layout Act[kt][l][e] = act[b=l&31][k]).
// acc row = 8p + 4*lhalf + type -> thread owns i,f,g,o for 4 consecutive j's
// (j = w*8 + 4*lhalf + p): activation lane-local AND h-write is 2x b64
// vector store (round 7 did 16 scalar b16 stores -> LDS-issue-bound).
// 3-term fp16-split MFMA (Wh*Ah + Wh*Al + Wl*Ah) == fp32 accuracy.
// ---------------------------------------------------------------------------
__global__ __launch_bounds__(1024) void lstm_kernel(
        const float* __restrict__ x,
        const float* __restrict__ Wp,
        const float* __restrict__ w_lin,
        const float* __restrict__ b_lin,
        float* __restrict__ s_out) {
    __shared__ __align__(16) _Float16 AHi[2][9][64][8];
    __shared__ __align__(16) _Float16 ALo[2][9][64][8];
    __shared__ float sred[15][32];

    const int tid   = threadIdx.x;
    const int lane  = tid & 63;
    const int w     = tid >> 6;        // wave 0..15
    const int l31   = lane & 31;
    const int lhalf = lane >> 5;
    const int n0    = blockIdx.x * 32;

    // ---- persistent weight fragments (waves 0..14): A-operand ----
    f16x8 bh[9], bl[9];
    if (w < 15) {
        const int p = w * 32 + l31;
#pragma unroll
        for (int kt = 0; kt < 9; ++kt) {
            const float* wp = Wp + p * 144 + kt * 16 + lhalf * 8;
            f16x8 hi, lo;
#pragma unroll
            for (int e = 0; e < 8; ++e) {
                float v = wp[e];
                _Float16 h_ = (_Float16)v;
                hi[e] = h_;
                lo[e] = (_Float16)(v - (float)h_);
            }
            bh[kt] = hi; bl[kt] = lo;
        }
    }

    // ---- zero h-region (kt 1..8) of both buffers: 1024 threads, 1:1 ----
    {
        f16x8 z;
#pragma unroll
        for (int e = 0; e < 8; ++e) z[e] = (_Float16)0.f;
        int bf = tid >> 9, kt = 1 + ((tid >> 6) & 7), ln = tid & 63;
        *(f16x8*)&AHi[bf][kt][ln][0] = z;
        *(f16x8*)&ALo[bf][kt][ln][0] = z;
    }
    __syncthreads();

    // ---- x staging geometry (wave 15): lane -> (row bx, half hx) ----
    const int bx = lane >> 1;
    const int hx = lane & 1;
    const int nx  = n0 + bx;
    const int bbx = nx / NSTOCK, ssx = nx % NSTOCK;
    const float* xbase = x + (size_t)bbx * 204800 + ssx * 16 + hx * 8;
    if (w == 15) {   // stage x_0 into buf 0
        float4 a0 = *(const float4*)xbase;
        float4 a1 = *(const float4*)(xbase + 4);
        float vv[8] = {a0.x, a0.y, a0.z, a0.w, a1.x, a1.y, a1.z, a1.w};
        f16x8 hi, lo;
#pragma unroll
        for (int e = 0; e < 8; ++e) {
            _Float16 h_ = (_Float16)vv[e];
            hi[e] = h_; lo[e] = (_Float16)(vv[e] - (float)h_);
        }
        *(f16x8*)&AHi[0][0][bx + 32 * hx][0] = hi;
        *(f16x8*)&ALo[0][0][bx + 32 * hx][0] = lo;
    }
    // ---- bias column: B[k=136][b] = 1.0, both buffers (never overwritten;
    //      k=136 -> kt=8, k15=8 -> ln = 32+b, e=0; ALo stays 0) ----
    if (tid < 64) {
        int buf = tid >> 5, b = tid & 31;
        AHi[buf][8][32 + b][0] = (_Float16)1.f;
    }
    __syncthreads();

    // ---- h-write constants: thread owns j = w*8 + 4*lhalf + p (p=0..3),
    //      batch = l31 -> AHi[wb][1+(w>>1)][l31+32*(w&1)][4*lhalf+p] ----
    const int ktw = 1 + (w >> 1);
    const int lnw = l31 + 32 * (w & 1);
    const int e0  = 4 * lhalf;

    float creg[4] = {0.f, 0.f, 0.f, 0.f};

    for (int t = 0; t < 128; ++t) {
        const int rb = t & 1;
        const int wb = rb ^ 1;
        if (w == 15) {
            // ---- stage x_{t+1} into write buffer ----
            int tt = (t < 127) ? t + 1 : 127;
            const float* xp = xbase + (size_t)tt * 1600;
            float4 a0 = *(const float4*)xp;
            float4 a1 = *(const float4*)(xp + 4);
            float vv[8] = {a0.x, a0.y, a0.z, a0.w, a1.x, a1.y, a1.z, a1.w};
            f16x8 hi, lo;
#pragma unroll
            for (int e = 0; e < 8; ++e) {
                _Float16 h_ = (_Float16)vv[e];
                hi[e] = h_; lo[e] = (_Float16)(vv[e] - (float)h_);
            }
            *(f16x8*)&AHi[wb][0][bx + 32 * hx][0] = hi;
            *(f16x8*)&ALo[wb][0][bx + 32 * hx][0] = lo;
        } else {
            // ---- GEMM: 27 MFMA, acc[4p+type] = preact(type, j=w*8+4*lhalf+p)
            f32x16 acc;
#pragma unroll
            for (int r = 0; r < 16; ++r) acc[r] = 0.f;
#pragma unroll
            for (int kt = 0; kt < 9; ++kt) {
                f16x8 ah = *(const f16x8*)&AHi[rb][kt][lane][0];
                f16x8 al = *(const f16x8*)&ALo[rb][kt][lane][0];
                acc = __builtin_amdgcn_mfma_f32_32x32x16_f16(bh[kt], ah, acc, 0, 0, 0);
                acc = __builtin_amdgcn_mfma_f32_32x32x16_f16(bh[kt], al, acc, 0, 0, 0);
                acc = __builtin_amdgcn_mfma_f32_32x32x16_f16(bl[kt], ah, acc, 0, 0, 0);
            }
            // ---- lane-local activation (scales/sign baked in weights) ----
            f16x4 hi4, lo4;
#pragma unroll
            for (int p = 0; p < 4; ++p) {
                float iv = rcpf(1.f + exp2f_(acc[4 * p + 0]));
                float fv = rcpf(1.f + exp2f_(acc[4 * p + 1]));
                float gv = 1.f - 2.f * rcpf(1.f + exp2f_(acc[4 * p + 2]));
                float ov = rcpf(1.f + exp2f_(acc[4 * p + 3]));
                float c = fv * creg[p] + iv * gv;
                creg[p] = c;
                float h = ov * (1.f - 2.f * rcpf(1.f + exp2f_(c * 2.8853900817779268f)));
                _Float16 hh = (_Float16)h;
                hi4[p] = hh;
                lo4[p] = (_Float16)(h - (float)hh);
            }
            // ---- h-write: two contiguous 8B vector stores ----
            *(f16x4*)&AHi[wb][ktw][lnw][e0] = hi4;
            *(f16x4*)&ALo[wb][ktw][lnw][e0] = lo4;
        }
        __syncthreads();
    }

    // ---- s = h_last . w_lin + b_lin  (final h is in buffer 0; layout
    //      position<->(batch,k) semantics unchanged by the j-remap) ----
    if (tid < 480) {
        const int b  = tid & 31;
        const int jg = tid >> 5;                 // 0..14, j = jg*8+e
        const int lane_ = b + 32 * (jg & 1);
        const int ktE = 1 + (jg >> 1);
        f16x8 hi = *(const f16x8*)&AHi[0][ktE][lane_][0];
        f16x8 lo = *(const f16x8*)&ALo[0][ktE][lane_][0];
        float sp = 0.f;
#pragma unroll
        for (int e = 0; e < 8; ++e)
            sp += ((float)hi[e] + (float)lo[e]) * w_lin[jg * 8 + e];
        sred[jg][b] = sp;
    }
    __syncthreads();
    if (tid < 32) {
        float s = b_lin[0];
#pragma unroll
        for (int jg2 = 0; jg2 < 15; ++jg2) s += sred[jg2][tid];
        s_out[n0 + tid] = s;
    }
}

// ---------------------------------------------------------------------------
// phat: per batch b, NeuralSort relaxed perm matrix -> fooT[m][b] (transposed)
// ---------------------------------------------------------------------------
__global__ __launch_bounds__(128) void phat_kernel(const float* __restrict__ s,
                                                   float* __restrict__ fooT) {
    __shared__ float a[NSTOCK], c[NSTOCK];
    const int b = blockIdx.x, tid = threadIdx.x;
    const float* sb = s + b * NSTOCK;
    if (tid < NSTOCK) {
        float sj = sb[tid];
        float rs = 0.f;
        for (int i2 = 0; i2 < NSTOCK; ++i2) rs += fabsf(sj - sb[i2]);
        a[tid] = sj * 0.2f;
        c[tid] = rs * 0.2f;
    }
    __syncthreads();
    if (tid < NSTOCK) {
        const int i = tid;
        const float sci = (float)(99 - 2 * i);
        float m = -1e30f;
        for (int j = 0; j < NSTOCK; ++j) m = fmaxf(m, sci * a[j] - c[j]);
        float sum = 0.f;
        for (int j = 0; j < NSTOCK; ++j) sum += __expf(sci * a[j] - c[j] - m);
        const float inv = 1.f / sum;
        for (int j = 0; j < NSTOCK; ++j)
            fooT[(size_t)(i * NSTOCK + j) * 64 + b] = __expf(sci * a[j] - c[j] - m) * inv;
    }
}

// ---------------------------------------------------------------------------
// mlp1: z2T[u][b] = relu(sum_m fooT[m][b]*W2[u][m] + b2[u])
// ---------------------------------------------------------------------------
__global__ __launch_bounds__(512) void mlp1_kernel(const float* __restrict__ fooT,
                                                   const float* __restrict__ W2,
                                                   const float* __restrict__ b2,
                                                   float* __restrict__ z2T) {
    __shared__ float part[8][4][64];
    const int tid = threadIdx.x;
    const int wv = tid >> 6, lane = tid & 63;
    const int u0 = blockIdx.x * 4;
    const int m0 = wv * 1250;
    float a0 = 0.f, a1 = 0.f, a2 = 0.f, a3 = 0.f;
    for (int mi = 0; mi < 1250; ++mi) {
        int m = m0 + mi;
        float v = fooT[(size_t)m * 64 + lane];
        a0 += v * W2[(size_t)(u0 + 0) * 10000 + m];
        a1 += v * W2[(size_t)(u0 + 1) * 10000 + m];
        a2 += v * W2[(size_t)(u0 + 2) * 10000 + m];
        a3 += v * W2[(size_t)(u0 + 3) * 10000 + m];
    }
    part[wv][0][lane] = a0; part[wv][1][lane] = a1;
    part[wv][2][lane] = a2; part[wv][3][lane] = a3;
    __syncthreads();
    if (tid < 256) {
        int q = tid >> 6, b = tid & 63;
        float s = b2[u0 + q];
#pragma unroll
        for (int w2 = 0; w2 < 8; ++w2) s += part[w2][q][b];
        z2T[(u0 + q) * 64 + b] = fmaxf(s, 0.f);
    }
}

// ---------------------------------------------------------------------------
// mlp2: z3[b][v] = sum_u z2[b][u]*W3[v][u] + b3[v]; out = softmax_v
// ---------------------------------------------------------------------------
__global__ __launch_bounds__(128) void mlp2_kernel(const float* __restrict__ z2T,
                                                   const float* __restrict__ W3,
                                                   const float* __restrict__ b3,
                                                   float* __restrict__ out) {
    __shared__ float zs[256];
    __shared__ float logits[NSTOCK];
    const int b = blockIdx.x, tid = threadIdx.x;
    for (int u = tid; u < 256; u += 128) zs[u] = z2T[u * 64 + b];
    __syncthreads();
    if (tid < NSTOCK) {
        float acc = b3[tid];
        const float* wr = W3 + tid * 256;
        for (int u = 0; u < 256; ++u) acc += zs[u] * wr[u];
        logits[tid] = acc;
    }
    __syncthreads();
    if (tid < NSTOCK) {
        float m = -1e30f;
        for (int j = 0; j < NSTOCK; ++j) m = fmaxf(m, logits[j]);
        float sum = 0.f;
        for (int j = 0; j < NSTOCK; ++j) sum += __expf(logits[j] - m);
        out[b * NSTOCK + tid] = __expf(logits[tid] - m) / sum;
    }
}

// ---------------------------------------------------------------------------
extern "C" void kernel_launch(void* const* d_in, const int* in_sizes, int n_in,
                              void* d_out, int out_size, void* d_ws, size_t ws_size,
                              hipStream_t stream) {
    const float* x     = (const float*)d_in[0];
    const float* W_ih  = (const float*)d_in[1];
    const float* W_hh  = (const float*)d_in[2];
    const float* b_ih  = (const float*)d_in[3];
    const float* b_hh  = (const float*)d_in[4];
    const float* w_lin = (const float*)d_in[5];
    const float* b_lin = (const float*)d_in[6];
    const float* W2    = (const float*)d_in[7];
    const float* b2    = (const float*)d_in[8];
    const float* W3    = (const float*)d_in[9];
    const float* b3    = (const float*)d_in[10];

    float* ws    = (float*)d_ws;
    float* Wp    = ws;                 // 480*144 = 69120
    float* sbuf  = ws + 69600;         // 6400
    float* fooT  = ws + 76000;         // 10000*64 = 640000
    float* z2T   = ws + 716000;        // 256*64 = 16384
    float* out   = (float*)d_out;

    prep_kernel<<<271, 256, 0, stream>>>(W_ih, W_hh, b_ih, b_hh, Wp);
    lstm_kernel<<<200, 1024, 0, stream>>>(x, Wp, w_lin, b_lin, sbuf);
    phat_kernel<<<64, 128, 0, stream>>>(sbuf, fooT);
    mlp1_kernel<<<64, 512, 0, stream>>>(fooT, W2, b2, z2T);
    mlp2_kernel<<<64, 128, 0, stream>>>(z2T, W3, b3, out);
}